// Round 1
// baseline (94.552 us; speedup 1.0000x reference)
//
#include <hip/hip_runtime.h>
#include <cstdint>
#include <cstddef>

#define BB 32
#define AA 8400
#define NBB 32
#define CC 80
#define TOPKN 10

// ---------------------------------------------------------------------------
// Kernel 1: per (b, j) block: compute align over all anchors, block top-10.
// align = pred_scores[b,a,cls]^1 * iou^6, zeroed unless (gt valid && anchor
// center strictly inside gt box). Ties broken by smaller anchor index to
// match jax.lax.top_k stability.
// ---------------------------------------------------------------------------
__global__ __launch_bounds__(256) void topk_kernel(
    const float* __restrict__ pred_scores, const float* __restrict__ pred_boxes,
    const float* __restrict__ anchor_points, const int* __restrict__ gt_labels,
    const float* __restrict__ gt_boxes, const int* __restrict__ gt_mask,
    int* __restrict__ topk_out) {
  const int j = blockIdx.x, b = blockIdx.y, t = threadIdx.x;
  const int g = b * NBB + j;
  const float gx0 = gt_boxes[g * 4 + 0], gy0 = gt_boxes[g * 4 + 1];
  const float gx1 = gt_boxes[g * 4 + 2], gy1 = gt_boxes[g * 4 + 3];
  const int cls = gt_labels[g];
  const bool gvalid = (gt_mask[g] != 0);
  const float ga1 = (gx1 - gx0) * (gy1 - gy0);

  float tv[TOPKN];
  int ti[TOPKN];
#pragma unroll
  for (int k = 0; k < TOPKN; k++) { tv[k] = -1.0f; ti[k] = 0x7fffffff; }

  for (int a = t; a < AA; a += 256) {
    const float apx = anchor_points[a * 2 + 0];
    const float apy = anchor_points[a * 2 + 1];
    const float d = fminf(fminf(apx - gx0, apy - gy0), fminf(gx1 - apx, gy1 - apy));
    float v = 0.0f;
    if (gvalid && d > 1e-8f) {
      const float* pb = pred_boxes + ((size_t)b * AA + a) * 4;
      const float p0 = pb[0], p1 = pb[1], p2 = pb[2], p3 = pb[3];
      const float iw = fmaxf(fminf(gx1, p2) - fmaxf(gx0, p0), 0.0f);
      const float ih = fmaxf(fminf(gy1, p3) - fmaxf(gy0, p1), 0.0f);
      const float inter = iw * ih;
      const float a2 = (p2 - p0) * (p3 - p1);
      const float iou = fmaxf(inter / (ga1 + a2 - inter + 1e-10f), 0.0f);
      const float s = pred_scores[((size_t)b * AA + a) * CC + cls];
      const float i2 = iou * iou;
      v = s * i2 * i2 * i2;
    }
    // insert (v, a) into the descending per-thread top-10
    if (v > tv[TOPKN - 1] || (v == tv[TOPKN - 1] && a < ti[TOPKN - 1])) {
      tv[TOPKN - 1] = v; ti[TOPKN - 1] = a;
#pragma unroll
      for (int k = TOPKN - 1; k > 0; k--) {
        if (tv[k] > tv[k - 1] || (tv[k] == tv[k - 1] && ti[k] < ti[k - 1])) {
          float fv = tv[k]; tv[k] = tv[k - 1]; tv[k - 1] = fv;
          int fi = ti[k]; ti[k] = ti[k - 1]; ti[k - 1] = fi;
        }
      }
    }
  }

  __shared__ float s_val[256][TOPKN];
  __shared__ int s_idx[256][TOPKN];
#pragma unroll
  for (int k = 0; k < TOPKN; k++) { s_val[t][k] = tv[k]; s_idx[t][k] = ti[k]; }
  __syncthreads();

  for (int stride = 128; stride >= 1; stride >>= 1) {
    if (t < stride) {
      float mv[TOPKN]; int mi[TOPKN];
      int p = 0, q = 0;
#pragma unroll
      for (int k = 0; k < TOPKN; k++) {
        const float v1 = s_val[t][p], v2 = s_val[t + stride][q];
        const int i1 = s_idx[t][p], i2 = s_idx[t + stride][q];
        const bool take1 = (v1 > v2) || (v1 == v2 && i1 <= i2);
        if (take1) { mv[k] = v1; mi[k] = i1; p++; }
        else       { mv[k] = v2; mi[k] = i2; q++; }
      }
#pragma unroll
      for (int k = 0; k < TOPKN; k++) { s_val[t][k] = mv[k]; s_idx[t][k] = mi[k]; }
    }
    __syncthreads();
  }
  if (t < TOPKN) topk_out[g * TOPKN + t] = s_idx[0][t];
}

// ---------------------------------------------------------------------------
// Kernel 2: per-anchor assignment.
//   cnt = #{valid gts whose top-10 contains a and anchor inside box}
//   cnt==0 -> -1 ; cnt==1 -> that gt ; cnt>1 -> argmax_j iou (first max)
// Also accumulates pos_align/pos_iou per gt via nonneg-float atomicMax.
// ---------------------------------------------------------------------------
__global__ __launch_bounds__(256) void assign_kernel(
    const float* __restrict__ pred_scores, const float* __restrict__ pred_boxes,
    const float* __restrict__ anchor_points, const int* __restrict__ gt_labels,
    const float* __restrict__ gt_boxes, const int* __restrict__ gt_mask,
    const int* __restrict__ topk_in,
    int* __restrict__ assign_out, float* __restrict__ align_out,
    int* __restrict__ pos_align, int* __restrict__ pos_iou) {
  const int b = blockIdx.y;
  const int t = threadIdx.x;
  const int a = blockIdx.x * 256 + t;

  __shared__ float sbox[NBB][4];
  __shared__ int scls[NBB];
  __shared__ int svalid[NBB];
  __shared__ int stk[NBB][TOPKN];

  if (t < NBB) {
    const int g = b * NBB + t;
    sbox[t][0] = gt_boxes[g * 4 + 0];
    sbox[t][1] = gt_boxes[g * 4 + 1];
    sbox[t][2] = gt_boxes[g * 4 + 2];
    sbox[t][3] = gt_boxes[g * 4 + 3];
    scls[t] = gt_labels[g];
    svalid[t] = (gt_mask[g] != 0) ? 1 : 0;
  }
  for (int i = t; i < NBB * TOPKN; i += 256)
    stk[i / TOPKN][i % TOPKN] = topk_in[b * NBB * TOPKN + i];
  __syncthreads();

  if (a >= AA) return;

  const float apx = anchor_points[a * 2 + 0];
  const float apy = anchor_points[a * 2 + 1];
  const float* pb = pred_boxes + ((size_t)b * AA + a) * 4;
  const float p0 = pb[0], p1 = pb[1], p2 = pb[2], p3 = pb[3];
  const float a2 = (p2 - p0) * (p3 - p1);

  int cnt = 0, last_j = 0, best_j = 0;
  float best_iou = -1.0f;
  for (int j = 0; j < NBB; j++) {
    const float gx0 = sbox[j][0], gy0 = sbox[j][1];
    const float gx1 = sbox[j][2], gy1 = sbox[j][3];
    const float d = fminf(fminf(apx - gx0, apy - gy0), fminf(gx1 - apx, gy1 - apy));
    const bool valid = svalid[j] && (d > 1e-8f);
    float iou = 0.0f;
    if (valid) {
      const float iw = fmaxf(fminf(gx1, p2) - fmaxf(gx0, p0), 0.0f);
      const float ih = fmaxf(fminf(gy1, p3) - fmaxf(gy0, p1), 0.0f);
      const float inter = iw * ih;
      const float a1 = (gx1 - gx0) * (gy1 - gy0);
      iou = fmaxf(inter / (a1 + a2 - inter + 1e-10f), 0.0f);
    }
    if (iou > best_iou) { best_iou = iou; best_j = j; }  // first-max semantics
    if (valid) {
      bool intk = false;
#pragma unroll
      for (int k = 0; k < TOPKN; k++) intk = intk || (stk[j][k] == a);
      if (intk) { cnt++; last_j = j; }
    }
  }

  const int assign = (cnt == 0) ? -1 : ((cnt == 1) ? last_j : best_j);
  float align_v = 0.0f;
  if (assign >= 0) {
    const int j = assign;
    const float gx0 = sbox[j][0], gy0 = sbox[j][1];
    const float gx1 = sbox[j][2], gy1 = sbox[j][3];
    const float iw = fmaxf(fminf(gx1, p2) - fmaxf(gx0, p0), 0.0f);
    const float ih = fmaxf(fminf(gy1, p3) - fmaxf(gy0, p1), 0.0f);
    const float inter = iw * ih;
    const float a1 = (gx1 - gx0) * (gy1 - gy0);
    const float iou = fmaxf(inter / (a1 + a2 - inter + 1e-10f), 0.0f);
    const float s = pred_scores[((size_t)b * AA + a) * CC + scls[j]];
    const float i2 = iou * iou;
    align_v = s * i2 * i2 * i2;
    atomicMax(&pos_align[b * NBB + j], __float_as_int(align_v));
    atomicMax(&pos_iou[b * NBB + j], __float_as_int(iou));
  }
  assign_out[b * AA + a] = assign;
  align_out[b * AA + a] = align_v;
}

// ---------------------------------------------------------------------------
// Kernel 3: finalize outputs (d_out pre-zeroed by memsetAsync).
// Layout: labels[B*A] | boxes[B*A*4] | scores[B*A*80] | fg[B*A], all f32.
// ---------------------------------------------------------------------------
__global__ __launch_bounds__(256) void finalize_kernel(
    const int* __restrict__ gt_labels, const float* __restrict__ gt_boxes,
    const int* __restrict__ assign_in, const float* __restrict__ align_in,
    const int* __restrict__ pos_align, const int* __restrict__ pos_iou,
    float* __restrict__ out) {
  const int idx = blockIdx.x * 256 + threadIdx.x;
  if (idx >= BB * AA) return;
  const int b = idx / AA;
  const int assign = assign_in[idx];
  const int j0 = (assign >= 0) ? assign : 0;
  const int g = b * NBB + j0;
  int label = gt_labels[g];
  label = min(max(label, 0), 80);

  float* out_labels = out;
  float* out_boxes = out + (size_t)BB * AA;
  float* out_scores = out + (size_t)BB * AA * 5;
  float* out_fg = out + (size_t)BB * AA * 85;

  out_labels[idx] = (float)label;
  out_boxes[(size_t)idx * 4 + 0] = gt_boxes[g * 4 + 0];
  out_boxes[(size_t)idx * 4 + 1] = gt_boxes[g * 4 + 1];
  out_boxes[(size_t)idx * 4 + 2] = gt_boxes[g * 4 + 2];
  out_boxes[(size_t)idx * 4 + 3] = gt_boxes[g * 4 + 3];
  out_fg[idx] = (assign >= 0) ? 1.0f : 0.0f;
  if (assign >= 0) {
    const float pa = __int_as_float(pos_align[b * NBB + assign]);
    const float pi = __int_as_float(pos_iou[b * NBB + assign]);
    const float norm = align_in[idx] * pi / (pa + 1e-8f);
    out_scores[(size_t)idx * CC + label] = norm;
  }
}

extern "C" void kernel_launch(void* const* d_in, const int* in_sizes, int n_in,
                              void* d_out, int out_size, void* d_ws, size_t ws_size,
                              hipStream_t stream) {
  const float* pred_scores = (const float*)d_in[0];
  const float* pred_boxes = (const float*)d_in[1];
  const float* anchor_points = (const float*)d_in[2];
  const int* gt_labels = (const int*)d_in[3];
  const float* gt_boxes = (const float*)d_in[4];
  const int* gt_mask = (const int*)d_in[5];
  float* out = (float*)d_out;

  char* ws = (char*)d_ws;
  int* topk = (int*)ws;                                    // B*NB*10 ints
  int* assign = (int*)(ws + 64 * 1024);                    // B*A ints
  float* align_v = (float*)(ws + 64 * 1024 + 1075200);     // B*A floats
  int* pos_align = (int*)(ws + 64 * 1024 + 2 * 1075200);   // B*NB ints(float bits)
  int* pos_iou = (int*)(ws + 64 * 1024 + 2 * 1075200 + 4096);  // B*NB

  hipMemsetAsync(d_out, 0, (size_t)out_size * sizeof(float), stream);
  hipMemsetAsync(pos_align, 0, 2 * 4096, stream);

  dim3 g1(NBB, BB);
  topk_kernel<<<g1, 256, 0, stream>>>(pred_scores, pred_boxes, anchor_points,
                                      gt_labels, gt_boxes, gt_mask, topk);

  dim3 g2((AA + 255) / 256, BB);
  assign_kernel<<<g2, 256, 0, stream>>>(pred_scores, pred_boxes, anchor_points,
                                        gt_labels, gt_boxes, gt_mask, topk,
                                        assign, align_v, pos_align, pos_iou);

  const int n = BB * AA;
  finalize_kernel<<<(n + 255) / 256, 256, 0, stream>>>(
      gt_labels, gt_boxes, assign, align_v, pos_align, pos_iou, out);
}

// Round 4
// 78.781 us; speedup vs baseline: 1.2002x; 1.2002x over previous
//
#include <hip/hip_runtime.h>
#include <cstdint>
#include <cstddef>

#define BB 32
#define AA 8400
#define NBB 32
#define CC 80
#define TOPKN 10
#define MAXC 1536  // >= max inside-anchors per gt: 33^2+17^2+9^2 = 1459

// ===========================================================================
// FAST PATH
// ===========================================================================

// Kernel A: compact candidates. One thread per (b, anchor); loop over 32 gts.
// Only "inside && gt-valid" pairs compute iou/score and append a sort key.
// key = (float_bits(align) << 32) | (8400 - a): descending uint64 order ==
// descending align with ties broken toward smaller anchor index (lax.top_k).
__global__ __launch_bounds__(256) void compact_kernel(
    const float* __restrict__ pred_scores, const float* __restrict__ pred_boxes,
    const float* __restrict__ anchor_points, const int* __restrict__ gt_labels,
    const float* __restrict__ gt_boxes, const int* __restrict__ gt_mask,
    unsigned long long* __restrict__ cand, int* __restrict__ cnt) {
  const int b = blockIdx.y, t = threadIdx.x;
  const int a = blockIdx.x * 256 + t;

  __shared__ float sbox[NBB][4];
  __shared__ int scls[NBB];
  __shared__ int svalid[NBB];
  if (t < NBB) {
    const int g = b * NBB + t;
    sbox[t][0] = gt_boxes[g * 4 + 0];
    sbox[t][1] = gt_boxes[g * 4 + 1];
    sbox[t][2] = gt_boxes[g * 4 + 2];
    sbox[t][3] = gt_boxes[g * 4 + 3];
    scls[t] = gt_labels[g];
    svalid[t] = (gt_mask[g] != 0) ? 1 : 0;
  }
  __syncthreads();
  if (a >= AA) return;

  const float apx = anchor_points[a * 2 + 0];
  const float apy = anchor_points[a * 2 + 1];
  const float* pb = pred_boxes + ((size_t)b * AA + a) * 4;
  const float p0 = pb[0], p1 = pb[1], p2 = pb[2], p3 = pb[3];
  const float a2 = (p2 - p0) * (p3 - p1);
  const float* srow = pred_scores + ((size_t)b * AA + a) * CC;

  for (int j = 0; j < NBB; j++) {
    if (!svalid[j]) continue;
    const float gx0 = sbox[j][0], gy0 = sbox[j][1];
    const float gx1 = sbox[j][2], gy1 = sbox[j][3];
    const float d = fminf(fminf(apx - gx0, apy - gy0), fminf(gx1 - apx, gy1 - apy));
    if (!(d > 1e-8f)) continue;
    const float iw = fmaxf(fminf(gx1, p2) - fmaxf(gx0, p0), 0.0f);
    const float ih = fmaxf(fminf(gy1, p3) - fmaxf(gy0, p1), 0.0f);
    const float inter = iw * ih;
    const float a1 = (gx1 - gx0) * (gy1 - gy0);
    const float iou = fmaxf(inter / (a1 + a2 - inter + 1e-10f), 0.0f);
    const float s = srow[scls[j]];
    const float i2 = iou * iou;
    const float align_v = s * i2 * i2 * i2;
    const int g = b * NBB + j;
    const int pos = atomicAdd(&cnt[g], 1);
    if (pos < MAXC) {
      const unsigned long long key =
          ((unsigned long long)__float_as_uint(align_v) << 32) |
          (unsigned int)(AA - a);
      cand[(size_t)g * MAXC + pos] = key;
    }
  }
}

// Kernel B: per (b,j): top-10 of compacted keys, scatter (1<<16)|j into acc.
__global__ __launch_bounds__(256) void top10_kernel(
    const unsigned long long* __restrict__ cand, const int* __restrict__ cnt,
    int* __restrict__ acc) {
  const int j = blockIdx.x, b = blockIdx.y, t = threadIdx.x;
  const int g = b * NBB + j;
  const int n = min(cnt[g], MAXC);

  unsigned long long tk[TOPKN];
#pragma unroll
  for (int k = 0; k < TOPKN; k++) tk[k] = 0ull;

  for (int i = t; i < n; i += 256) {
    const unsigned long long key = cand[(size_t)g * MAXC + i];
    if (key > tk[TOPKN - 1]) {
      tk[TOPKN - 1] = key;
#pragma unroll
      for (int k = TOPKN - 1; k > 0; k--) {
        if (tk[k] > tk[k - 1]) {
          unsigned long long tmp = tk[k]; tk[k] = tk[k - 1]; tk[k - 1] = tmp;
        }
      }
    }
  }

  __shared__ unsigned long long s_key[256][TOPKN];
#pragma unroll
  for (int k = 0; k < TOPKN; k++) s_key[t][k] = tk[k];
  __syncthreads();

  for (int stride = 128; stride >= 1; stride >>= 1) {
    if (t < stride) {
      unsigned long long mk[TOPKN];
      int p = 0, q = 0;
#pragma unroll
      for (int k = 0; k < TOPKN; k++) {
        const unsigned long long k1 = s_key[t][p], k2 = s_key[t + stride][q];
        if (k1 >= k2) { mk[k] = k1; p++; } else { mk[k] = k2; q++; }
      }
#pragma unroll
      for (int k = 0; k < TOPKN; k++) s_key[t][k] = mk[k];
    }
    __syncthreads();
  }

  if (t < TOPKN) {
    const unsigned long long key = s_key[0][t];
    if (key != 0ull) {
      const int a = AA - (int)(key & 0xffffffffu);
      atomicAdd(&acc[b * AA + a], 65536 + j);
    }
  }
}

// Kernel C: per-anchor conflict resolution + pos_align/pos_iou atomics.
__global__ __launch_bounds__(256) void resolve_kernel(
    const float* __restrict__ pred_scores, const float* __restrict__ pred_boxes,
    const int* __restrict__ gt_labels, const float* __restrict__ gt_boxes,
    const int* __restrict__ gt_mask, const float* __restrict__ anchor_points,
    const int* __restrict__ acc,
    int* __restrict__ assign_out, float* __restrict__ align_out,
    int* __restrict__ pos_align, int* __restrict__ pos_iou) {
  const int b = blockIdx.y, t = threadIdx.x;
  const int a = blockIdx.x * 256 + t;

  __shared__ float sbox[NBB][4];
  __shared__ int scls[NBB];
  __shared__ int svalid[NBB];
  if (t < NBB) {
    const int g = b * NBB + t;
    sbox[t][0] = gt_boxes[g * 4 + 0];
    sbox[t][1] = gt_boxes[g * 4 + 1];
    sbox[t][2] = gt_boxes[g * 4 + 2];
    sbox[t][3] = gt_boxes[g * 4 + 3];
    scls[t] = gt_labels[g];
    svalid[t] = (gt_mask[g] != 0) ? 1 : 0;
  }
  __syncthreads();
  if (a >= AA) return;

  const int v = acc[b * AA + a];
  const int cntv = v >> 16;
  int assign = -1;
  float align_v = 0.0f;

  if (cntv > 0) {
    const float apx = anchor_points[a * 2 + 0];
    const float apy = anchor_points[a * 2 + 1];
    const float* pbp = pred_boxes + ((size_t)b * AA + a) * 4;
    const float p0 = pbp[0], p1 = pbp[1], p2 = pbp[2], p3 = pbp[3];
    const float a2 = (p2 - p0) * (p3 - p1);

    if (cntv == 1) {
      assign = v & 0xffff;
    } else {
      // argmax_j of (iou * valid), first-max semantics
      float best_iou = -1.0f;
      int best_j = 0;
      for (int j = 0; j < NBB; j++) {
        const float gx0 = sbox[j][0], gy0 = sbox[j][1];
        const float gx1 = sbox[j][2], gy1 = sbox[j][3];
        const float d = fminf(fminf(apx - gx0, apy - gy0), fminf(gx1 - apx, gy1 - apy));
        float iou = 0.0f;
        if (svalid[j] && d > 1e-8f) {
          const float iw = fmaxf(fminf(gx1, p2) - fmaxf(gx0, p0), 0.0f);
          const float ih = fmaxf(fminf(gy1, p3) - fmaxf(gy0, p1), 0.0f);
          const float inter = iw * ih;
          const float a1 = (gx1 - gx0) * (gy1 - gy0);
          iou = fmaxf(inter / (a1 + a2 - inter + 1e-10f), 0.0f);
        }
        if (iou > best_iou) { best_iou = iou; best_j = j; }
      }
      assign = best_j;
    }

    const int j = assign;
    const float gx0 = sbox[j][0], gy0 = sbox[j][1];
    const float gx1 = sbox[j][2], gy1 = sbox[j][3];
    const float iw = fmaxf(fminf(gx1, p2) - fmaxf(gx0, p0), 0.0f);
    const float ih = fmaxf(fminf(gy1, p3) - fmaxf(gy0, p1), 0.0f);
    const float inter = iw * ih;
    const float a1 = (gx1 - gx0) * (gy1 - gy0);
    const float iou = fmaxf(inter / (a1 + a2 - inter + 1e-10f), 0.0f);
    const float s = pred_scores[((size_t)b * AA + a) * CC + scls[j]];
    const float i2 = iou * iou;
    align_v = s * i2 * i2 * i2;
    atomicMax(&pos_align[b * NBB + j], __float_as_int(align_v));
    atomicMax(&pos_iou[b * NBB + j], __float_as_int(iou));
  }
  assign_out[b * AA + a] = assign;
  align_out[b * AA + a] = align_v;
}

// Kernel D: write the whole output (no memset needed). One thread per float4
// chunk of the scores tensor (20 chunks/anchor); chunk 0's thread also writes
// label, box, fg for its anchor.
__global__ __launch_bounds__(256) void write_out_kernel(
    const int* __restrict__ gt_labels, const float* __restrict__ gt_boxes,
    const int* __restrict__ assign_in, const float* __restrict__ align_in,
    const int* __restrict__ pos_align, const int* __restrict__ pos_iou,
    float* __restrict__ out) {
  const int idx = blockIdx.x * 256 + threadIdx.x;  // [0, BB*AA*20)
  const int aidx = idx / 20;                        // anchor index in [0, BB*AA)
  const int c = idx - aidx * 20;                    // float4 chunk in row
  const int b = aidx / AA;

  const int assign = assign_in[aidx];
  const int j0 = (assign >= 0) ? assign : 0;
  const int g = b * NBB + j0;
  int label = gt_labels[g];
  label = min(max(label, 0), 80);

  float* out_scores = out + (size_t)BB * AA * 5;
  float4 vv = make_float4(0.f, 0.f, 0.f, 0.f);
  if (assign >= 0 && c == (label >> 2)) {
    const float pa = __int_as_float(pos_align[b * NBB + assign]);
    const float pi = __int_as_float(pos_iou[b * NBB + assign]);
    const float norm = align_in[aidx] * pi / (pa + 1e-8f);
    ((float*)&vv)[label & 3] = norm;
  }
  reinterpret_cast<float4*>(out_scores)[(size_t)aidx * 20 + c] = vv;

  if (c == 0) {
    out[aidx] = (float)label;                               // labels
    float* out_boxes = out + (size_t)BB * AA;
    out_boxes[(size_t)aidx * 4 + 0] = gt_boxes[g * 4 + 0];
    out_boxes[(size_t)aidx * 4 + 1] = gt_boxes[g * 4 + 1];
    out_boxes[(size_t)aidx * 4 + 2] = gt_boxes[g * 4 + 2];
    out_boxes[(size_t)aidx * 4 + 3] = gt_boxes[g * 4 + 3];
    out[(size_t)BB * AA * 85 + aidx] = (assign >= 0) ? 1.0f : 0.0f;  // fg
  }
}

// ===========================================================================
// FALLBACK PATH (round-1 kernels, used only if ws_size is too small)
// ===========================================================================
__global__ __launch_bounds__(256) void topk_kernel(
    const float* __restrict__ pred_scores, const float* __restrict__ pred_boxes,
    const float* __restrict__ anchor_points, const int* __restrict__ gt_labels,
    const float* __restrict__ gt_boxes, const int* __restrict__ gt_mask,
    int* __restrict__ topk_out) {
  const int j = blockIdx.x, b = blockIdx.y, t = threadIdx.x;
  const int g = b * NBB + j;
  const float gx0 = gt_boxes[g * 4 + 0], gy0 = gt_boxes[g * 4 + 1];
  const float gx1 = gt_boxes[g * 4 + 2], gy1 = gt_boxes[g * 4 + 3];
  const int cls = gt_labels[g];
  const bool gvalid = (gt_mask[g] != 0);
  const float ga1 = (gx1 - gx0) * (gy1 - gy0);

  float tv[TOPKN];
  int ti[TOPKN];
#pragma unroll
  for (int k = 0; k < TOPKN; k++) { tv[k] = -1.0f; ti[k] = 0x7fffffff; }

  for (int a = t; a < AA; a += 256) {
    const float apx = anchor_points[a * 2 + 0];
    const float apy = anchor_points[a * 2 + 1];
    const float d = fminf(fminf(apx - gx0, apy - gy0), fminf(gx1 - apx, gy1 - apy));
    float v = 0.0f;
    if (gvalid && d > 1e-8f) {
      const float* pb = pred_boxes + ((size_t)b * AA + a) * 4;
      const float p0 = pb[0], p1 = pb[1], p2 = pb[2], p3 = pb[3];
      const float iw = fmaxf(fminf(gx1, p2) - fmaxf(gx0, p0), 0.0f);
      const float ih = fmaxf(fminf(gy1, p3) - fmaxf(gy0, p1), 0.0f);
      const float inter = iw * ih;
      const float a2 = (p2 - p0) * (p3 - p1);
      const float iou = fmaxf(inter / (ga1 + a2 - inter + 1e-10f), 0.0f);
      const float s = pred_scores[((size_t)b * AA + a) * CC + cls];
      const float i2 = iou * iou;
      v = s * i2 * i2 * i2;
    }
    if (v > tv[TOPKN - 1] || (v == tv[TOPKN - 1] && a < ti[TOPKN - 1])) {
      tv[TOPKN - 1] = v; ti[TOPKN - 1] = a;
#pragma unroll
      for (int k = TOPKN - 1; k > 0; k--) {
        if (tv[k] > tv[k - 1] || (tv[k] == tv[k - 1] && ti[k] < ti[k - 1])) {
          float fv = tv[k]; tv[k] = tv[k - 1]; tv[k - 1] = fv;
          int fi = ti[k]; ti[k] = ti[k - 1]; ti[k - 1] = fi;
        }
      }
    }
  }

  __shared__ float s_val[256][TOPKN];
  __shared__ int s_idx[256][TOPKN];
#pragma unroll
  for (int k = 0; k < TOPKN; k++) { s_val[t][k] = tv[k]; s_idx[t][k] = ti[k]; }
  __syncthreads();

  for (int stride = 128; stride >= 1; stride >>= 1) {
    if (t < stride) {
      float mv[TOPKN]; int mi[TOPKN];
      int p = 0, q = 0;
#pragma unroll
      for (int k = 0; k < TOPKN; k++) {
        const float v1 = s_val[t][p], v2 = s_val[t + stride][q];
        const int i1 = s_idx[t][p], i2 = s_idx[t + stride][q];
        const bool take1 = (v1 > v2) || (v1 == v2 && i1 <= i2);
        if (take1) { mv[k] = v1; mi[k] = i1; p++; }
        else       { mv[k] = v2; mi[k] = i2; q++; }
      }
#pragma unroll
      for (int k = 0; k < TOPKN; k++) { s_val[t][k] = mv[k]; s_idx[t][k] = mi[k]; }
    }
    __syncthreads();
  }
  if (t < TOPKN) topk_out[g * TOPKN + t] = s_idx[0][t];
}

__global__ __launch_bounds__(256) void assign_kernel(
    const float* __restrict__ pred_scores, const float* __restrict__ pred_boxes,
    const float* __restrict__ anchor_points, const int* __restrict__ gt_labels,
    const float* __restrict__ gt_boxes, const int* __restrict__ gt_mask,
    const int* __restrict__ topk_in,
    int* __restrict__ assign_out, float* __restrict__ align_out,
    int* __restrict__ pos_align, int* __restrict__ pos_iou) {
  const int b = blockIdx.y;
  const int t = threadIdx.x;
  const int a = blockIdx.x * 256 + t;

  __shared__ float sbox[NBB][4];
  __shared__ int scls[NBB];
  __shared__ int svalid[NBB];
  __shared__ int stk[NBB][TOPKN];

  if (t < NBB) {
    const int g = b * NBB + t;
    sbox[t][0] = gt_boxes[g * 4 + 0];
    sbox[t][1] = gt_boxes[g * 4 + 1];
    sbox[t][2] = gt_boxes[g * 4 + 2];
    sbox[t][3] = gt_boxes[g * 4 + 3];
    scls[t] = gt_labels[g];
    svalid[t] = (gt_mask[g] != 0) ? 1 : 0;
  }
  for (int i = t; i < NBB * TOPKN; i += 256)
    stk[i / TOPKN][i % TOPKN] = topk_in[b * NBB * TOPKN + i];
  __syncthreads();

  if (a >= AA) return;

  const float apx = anchor_points[a * 2 + 0];
  const float apy = anchor_points[a * 2 + 1];
  const float* pb = pred_boxes + ((size_t)b * AA + a) * 4;
  const float p0 = pb[0], p1 = pb[1], p2 = pb[2], p3 = pb[3];
  const float a2 = (p2 - p0) * (p3 - p1);

  int cnt = 0, last_j = 0, best_j = 0;
  float best_iou = -1.0f;
  for (int j = 0; j < NBB; j++) {
    const float gx0 = sbox[j][0], gy0 = sbox[j][1];
    const float gx1 = sbox[j][2], gy1 = sbox[j][3];
    const float d = fminf(fminf(apx - gx0, apy - gy0), fminf(gx1 - apx, gy1 - apy));
    const bool valid = svalid[j] && (d > 1e-8f);
    float iou = 0.0f;
    if (valid) {
      const float iw = fmaxf(fminf(gx1, p2) - fmaxf(gx0, p0), 0.0f);
      const float ih = fmaxf(fminf(gy1, p3) - fmaxf(gy0, p1), 0.0f);
      const float inter = iw * ih;
      const float a1 = (gx1 - gx0) * (gy1 - gy0);
      iou = fmaxf(inter / (a1 + a2 - inter + 1e-10f), 0.0f);
    }
    if (iou > best_iou) { best_iou = iou; best_j = j; }
    if (valid) {
      bool intk = false;
#pragma unroll
      for (int k = 0; k < TOPKN; k++) intk = intk || (stk[j][k] == a);
      if (intk) { cnt++; last_j = j; }
    }
  }

  const int assign = (cnt == 0) ? -1 : ((cnt == 1) ? last_j : best_j);
  float align_v = 0.0f;
  if (assign >= 0) {
    const int j = assign;
    const float gx0 = sbox[j][0], gy0 = sbox[j][1];
    const float gx1 = sbox[j][2], gy1 = sbox[j][3];
    const float iw = fmaxf(fminf(gx1, p2) - fmaxf(gx0, p0), 0.0f);
    const float ih = fmaxf(fminf(gy1, p3) - fmaxf(gy0, p1), 0.0f);
    const float inter = iw * ih;
    const float a1 = (gx1 - gx0) * (gy1 - gy0);
    const float iou = fmaxf(inter / (a1 + a2 - inter + 1e-10f), 0.0f);
    const float s = pred_scores[((size_t)b * AA + a) * CC + scls[j]];
    const float i2 = iou * iou;
    align_v = s * i2 * i2 * i2;
    atomicMax(&pos_align[b * NBB + j], __float_as_int(align_v));
    atomicMax(&pos_iou[b * NBB + j], __float_as_int(iou));
  }
  assign_out[b * AA + a] = assign;
  align_out[b * AA + a] = align_v;
}

__global__ __launch_bounds__(256) void finalize_kernel(
    const int* __restrict__ gt_labels, const float* __restrict__ gt_boxes,
    const int* __restrict__ assign_in, const float* __restrict__ align_in,
    const int* __restrict__ pos_align, const int* __restrict__ pos_iou,
    float* __restrict__ out) {
  const int idx = blockIdx.x * 256 + threadIdx.x;
  if (idx >= BB * AA) return;
  const int b = idx / AA;
  const int assign = assign_in[idx];
  const int j0 = (assign >= 0) ? assign : 0;
  const int g = b * NBB + j0;
  int label = gt_labels[g];
  label = min(max(label, 0), 80);

  float* out_boxes = out + (size_t)BB * AA;
  float* out_scores = out + (size_t)BB * AA * 5;
  float* out_fg = out + (size_t)BB * AA * 85;

  out[idx] = (float)label;
  out_boxes[(size_t)idx * 4 + 0] = gt_boxes[g * 4 + 0];
  out_boxes[(size_t)idx * 4 + 1] = gt_boxes[g * 4 + 1];
  out_boxes[(size_t)idx * 4 + 2] = gt_boxes[g * 4 + 2];
  out_boxes[(size_t)idx * 4 + 3] = gt_boxes[g * 4 + 3];
  out_fg[idx] = (assign >= 0) ? 1.0f : 0.0f;
  if (assign >= 0) {
    const float pa = __int_as_float(pos_align[b * NBB + assign]);
    const float pi = __int_as_float(pos_iou[b * NBB + assign]);
    const float norm = align_in[idx] * pi / (pa + 1e-8f);
    out_scores[(size_t)idx * CC + label] = norm;
  }
}

// ===========================================================================
extern "C" void kernel_launch(void* const* d_in, const int* in_sizes, int n_in,
                              void* d_out, int out_size, void* d_ws, size_t ws_size,
                              hipStream_t stream) {
  const float* pred_scores = (const float*)d_in[0];
  const float* pred_boxes = (const float*)d_in[1];
  const float* anchor_points = (const float*)d_in[2];
  const int* gt_labels = (const int*)d_in[3];
  const float* gt_boxes = (const float*)d_in[4];
  const int* gt_mask = (const int*)d_in[5];
  float* out = (float*)d_out;
  char* ws = (char*)d_ws;

  // fast-path workspace layout (bytes)
  const size_t off_cand = 0;                                   // 1024*MAXC*8
  const size_t off_cnt = off_cand + (size_t)BB * NBB * MAXC * 8;  // 4096
  const size_t off_acc = off_cnt + 4096;                       // BB*AA*4
  const size_t off_posA = off_acc + (size_t)BB * AA * 4;       // 4096
  const size_t off_posI = off_posA + 4096;                     // 4096
  const size_t off_assign = off_posI + 4096;                   // BB*AA*4
  const size_t off_align = off_assign + (size_t)BB * AA * 4;   // BB*AA*4
  const size_t req = off_align + (size_t)BB * AA * 4;

  if (ws_size >= req) {
    unsigned long long* cand = (unsigned long long*)(ws + off_cand);
    int* cnt = (int*)(ws + off_cnt);
    int* acc = (int*)(ws + off_acc);
    int* posA = (int*)(ws + off_posA);
    int* posI = (int*)(ws + off_posI);
    int* assign = (int*)(ws + off_assign);
    float* align_v = (float*)(ws + off_align);

    // zero cnt + acc + posA + posI (contiguous)
    hipMemsetAsync(ws + off_cnt, 0, off_assign - off_cnt, stream);

    dim3 gA((AA + 255) / 256, BB);
    compact_kernel<<<gA, 256, 0, stream>>>(pred_scores, pred_boxes,
                                           anchor_points, gt_labels, gt_boxes,
                                           gt_mask, cand, cnt);

    dim3 gB(NBB, BB);
    top10_kernel<<<gB, 256, 0, stream>>>(cand, cnt, acc);

    dim3 gC((AA + 255) / 256, BB);
    resolve_kernel<<<gC, 256, 0, stream>>>(pred_scores, pred_boxes, gt_labels,
                                           gt_boxes, gt_mask, anchor_points,
                                           acc, assign, align_v, posA, posI);

    const int nchunks = BB * AA * 20;
    write_out_kernel<<<(nchunks + 255) / 256, 256, 0, stream>>>(
        gt_labels, gt_boxes, assign, align_v, posA, posI, out);
  } else {
    // fallback (round-1 path)
    int* topk = (int*)ws;
    int* assign = (int*)(ws + 64 * 1024);
    float* align_v = (float*)(ws + 64 * 1024 + 1075200);
    int* posA = (int*)(ws + 64 * 1024 + 2 * 1075200);
    int* posI = (int*)(ws + 64 * 1024 + 2 * 1075200 + 4096);

    hipMemsetAsync(d_out, 0, (size_t)out_size * sizeof(float), stream);
    hipMemsetAsync(posA, 0, 2 * 4096, stream);

    dim3 g1(NBB, BB);
    topk_kernel<<<g1, 256, 0, stream>>>(pred_scores, pred_boxes, anchor_points,
                                        gt_labels, gt_boxes, gt_mask, topk);
    dim3 g2((AA + 255) / 256, BB);
    assign_kernel<<<g2, 256, 0, stream>>>(pred_scores, pred_boxes,
                                          anchor_points, gt_labels, gt_boxes,
                                          gt_mask, topk, assign, align_v, posA,
                                          posI);
    const int n = BB * AA;
    finalize_kernel<<<(n + 255) / 256, 256, 0, stream>>>(
        gt_labels, gt_boxes, assign, align_v, posA, posI, out);
  }
}